// Round 3
// baseline (111.504 us; speedup 1.0000x reference)
//
#include <hip/hip_runtime.h>

#define N_SENT 1024
#define LSEQ   128
#define HDIM   768
#define KSPAN  5
#define TPB    192   // HDIM / 4 float4 lanes
#define UNROLL 8
#define NITEMS (2 * N_SENT)
#define NBLOCKS 1024

__global__ __launch_bounds__(TPB) void bert_pool_kernel(
    const float* __restrict__ review_feat,   // [N, L, H]
    const float* __restrict__ reply_feat,    // [N, L, H]
    const int*   __restrict__ review_nt,     // [N]
    const int*   __restrict__ reply_nt,      // [N]
    const int*   __restrict__ review_ss,     // [N, K]
    const int*   __restrict__ review_se,     // [N, K]
    const int*   __restrict__ reply_ss,      // [N, K]
    const int*   __restrict__ reply_se,      // [N, K]
    float*       __restrict__ out,           // [4, N, H]: review_pt, review_sent, reply_pt, reply_sent
    int*         __restrict__ ctr)           // work-stealing counter (zeroed before launch)
{
    const int tid = threadIdx.x;
    __shared__ int item_s;

    for (;;) {
        if (tid == 0) item_s = atomicAdd(ctr, 1);
        __syncthreads();
        const int item = item_s;
        __syncthreads();
        if (item >= NITEMS) return;

        const int  n        = item >> 1;
        const bool is_reply = (item & 1) != 0;

        const float* feat = is_reply ? reply_feat : review_feat;
        const int*   ntp  = is_reply ? reply_nt   : review_nt;
        const int*   ssp  = is_reply ? reply_ss   : review_ss;
        const int*   sep  = is_reply ? reply_se   : review_se;
        float* out_pt   = out + (is_reply ? 2 : 0) * (size_t)N_SENT * HDIM;
        float* out_sent = out + (is_reply ? 3 : 1) * (size_t)N_SENT * HDIM;

        const int nt = ntp[n];

        int s[KSPAN], e[KSPAN];
        int l_lo = 1, l_hi = nt;
#pragma unroll
        for (int k = 0; k < KSPAN; ++k) {
            s[k] = ssp[(size_t)n * KSPAN + k];
            e[k] = sep[(size_t)n * KSPAN + k];
            if (s[k] <= e[k]) {              // valid span
                if (s[k] < l_lo) l_lo = s[k];
                if (e[k] > l_hi) l_hi = e[k];
            }
        }
        if (l_lo < 0) l_lo = 0;
        if (l_hi > LSEQ - 1) l_hi = LSEQ - 1;

        const float4* frow = (const float4*)(feat + (size_t)n * LSEQ * HDIM);

        float sx = 0.f, sy = 0.f, sz = 0.f, sw = 0.f;   // sentence accum
        float px = 0.f, py = 0.f, pz = 0.f, pw = 0.f;   // span accum
        float span_cnt = 0.f;

        for (int l0 = l_lo; l0 <= l_hi; l0 += UNROLL) {
            float4 v[UNROLL];
            float  ms[UNROLL], mp[UNROLL];
#pragma unroll
            for (int i = 0; i < UNROLL; ++i) {
                const int  l    = l0 + i;
                const bool live = (l <= l_hi);
                const int  lc   = live ? l : l_hi;       // clamped dup -> L1 hit
                v[i] = frow[(size_t)lc * (HDIM / 4) + tid];
                ms[i] = (live && l >= 1 && l <= nt) ? 1.0f : 0.0f;
                bool insp = false;
#pragma unroll
                for (int k = 0; k < KSPAN; ++k)
                    insp = insp || ((l >= s[k]) && (l <= e[k]));
                mp[i] = (live && insp) ? 1.0f : 0.0f;
            }
#pragma unroll
            for (int i = 0; i < UNROLL; ++i) {
                sx = fmaf(v[i].x, ms[i], sx);
                sy = fmaf(v[i].y, ms[i], sy);
                sz = fmaf(v[i].z, ms[i], sz);
                sw = fmaf(v[i].w, ms[i], sw);
                px = fmaf(v[i].x, mp[i], px);
                py = fmaf(v[i].y, mp[i], py);
                pz = fmaf(v[i].z, mp[i], pz);
                pw = fmaf(v[i].w, mp[i], pw);
                span_cnt += mp[i];
            }
        }

        const float sent_cnt = (float)(nt < LSEQ - 1 ? nt : LSEQ - 1);
        const float inv_s = 1.0f / sent_cnt;
        const float smx = sx * inv_s, smy = sy * inv_s, smz = sz * inv_s, smw = sw * inv_s;

        const bool  has_span = (span_cnt > 0.5f);
        const float inv_p = 1.0f / fmaxf(span_cnt, 1.0f);
        const float ptx = has_span ? px * inv_p : smx;
        const float pty = has_span ? py * inv_p : smy;
        const float ptz = has_span ? pz * inv_p : smz;
        const float ptw = has_span ? pw * inv_p : smw;

        float4* opt = (float4*)(out_pt   + (size_t)n * HDIM);
        float4* osn = (float4*)(out_sent + (size_t)n * HDIM);
        opt[tid] = make_float4(ptx, pty, ptz, ptw);
        osn[tid] = make_float4(smx, smy, smz, smw);
    }
}

extern "C" void kernel_launch(void* const* d_in, const int* in_sizes, int n_in,
                              void* d_out, int out_size, void* d_ws, size_t ws_size,
                              hipStream_t stream) {
    const float* review_feat = (const float*)d_in[0];
    const float* reply_feat  = (const float*)d_in[1];
    const int*   review_nt   = (const int*)d_in[2];
    const int*   reply_nt    = (const int*)d_in[3];
    const int*   review_ss   = (const int*)d_in[4];
    const int*   review_se   = (const int*)d_in[5];
    const int*   reply_ss    = (const int*)d_in[6];
    const int*   reply_se    = (const int*)d_in[7];
    float* out = (float*)d_out;
    int*   ctr = (int*)d_ws;

    hipMemsetAsync(ctr, 0, sizeof(int), stream);
    bert_pool_kernel<<<NBLOCKS, TPB, 0, stream>>>(
        review_feat, reply_feat, review_nt, reply_nt,
        review_ss, review_se, reply_ss, reply_se, out, ctr);
}

// Round 4
// 107.628 us; speedup vs baseline: 1.0360x; 1.0360x over previous
//
#include <hip/hip_runtime.h>

#define N_SENT 1024
#define LSEQ   128
#define HDIM   768
#define KSPAN  5
#define TPB    192      // HDIM / 4 float4 lanes
#define UNROLL 8
#define CHUNK  32       // rows per phase-1 block
#define NCHUNK (LSEQ / CHUNK)   // 4
// ws layout: [2*N_SENT items][NCHUNK][2][HDIM] floats, then counts [2*N_SENT][NCHUNK]
#define SLOT_FLOATS (2 * HDIM)
#define CNT_OFFSET  ((size_t)2 * N_SENT * NCHUNK * SLOT_FLOATS)

__device__ __forceinline__ void load_meta(
    const int* ntp, const int* ssp, const int* sep, int n,
    int& nt, int* s, int* e, int& l_lo, int& l_hi)
{
    nt = ntp[n];
    l_lo = 1; l_hi = nt;
#pragma unroll
    for (int k = 0; k < KSPAN; ++k) {
        s[k] = ssp[(size_t)n * KSPAN + k];
        e[k] = sep[(size_t)n * KSPAN + k];
        if (s[k] <= e[k]) {
            if (s[k] < l_lo) l_lo = s[k];
            if (e[k] > l_hi) l_hi = e[k];
        }
    }
    if (l_lo < 0) l_lo = 0;
    if (l_hi > LSEQ - 1) l_hi = LSEQ - 1;
}

__global__ __launch_bounds__(TPB) void pool_phase1(
    const float* __restrict__ review_feat,
    const float* __restrict__ reply_feat,
    const int*   __restrict__ review_nt,
    const int*   __restrict__ reply_nt,
    const int*   __restrict__ review_ss,
    const int*   __restrict__ review_se,
    const int*   __restrict__ reply_ss,
    const int*   __restrict__ reply_se,
    float*       __restrict__ ws)
{
    const int n   = blockIdx.x;
    const int tid = threadIdx.x;
    const bool is_reply = (blockIdx.y != 0);
    const int c   = blockIdx.z;

    const float* feat = is_reply ? reply_feat : review_feat;
    const int*   ntp  = is_reply ? reply_nt   : review_nt;
    const int*   ssp  = is_reply ? reply_ss   : review_ss;
    const int*   sep  = is_reply ? reply_se   : review_se;

    int nt, s[KSPAN], e[KSPAN], l_lo, l_hi;
    load_meta(ntp, ssp, sep, n, nt, s, e, l_lo, l_hi);

    const int c0 = c * CHUNK;
    const int r0 = l_lo > c0 ? l_lo : c0;
    const int r1 = l_hi < c0 + CHUNK - 1 ? l_hi : c0 + CHUNK - 1;
    if (r0 > r1) return;   // inactive chunk: phase 2 won't read this slot

    const float4* frow = (const float4*)(feat + (size_t)n * LSEQ * HDIM);

    float sx = 0.f, sy = 0.f, sz = 0.f, sw = 0.f;
    float px = 0.f, py = 0.f, pz = 0.f, pw = 0.f;
    float span_cnt = 0.f;

    for (int l0 = r0; l0 <= r1; l0 += UNROLL) {
        float4 v[UNROLL];
        float  ms[UNROLL], mp[UNROLL];
#pragma unroll
        for (int i = 0; i < UNROLL; ++i) {
            const int  l    = l0 + i;
            const bool live = (l <= r1);
            const int  lc   = live ? l : r1;   // clamped dup -> L1 hit
            v[i] = frow[(size_t)lc * (HDIM / 4) + tid];
            ms[i] = (live && l >= 1 && l <= nt) ? 1.0f : 0.0f;
            bool insp = false;
#pragma unroll
            for (int k = 0; k < KSPAN; ++k)
                insp = insp || ((l >= s[k]) && (l <= e[k]));
            mp[i] = (live && insp) ? 1.0f : 0.0f;
        }
#pragma unroll
        for (int i = 0; i < UNROLL; ++i) {
            sx = fmaf(v[i].x, ms[i], sx);
            sy = fmaf(v[i].y, ms[i], sy);
            sz = fmaf(v[i].z, ms[i], sz);
            sw = fmaf(v[i].w, ms[i], sw);
            px = fmaf(v[i].x, mp[i], px);
            py = fmaf(v[i].y, mp[i], py);
            pz = fmaf(v[i].z, mp[i], pz);
            pw = fmaf(v[i].w, mp[i], pw);
            span_cnt += mp[i];
        }
    }

    const int item = (is_reply ? N_SENT : 0) + n;
    const size_t slot = (size_t)item * NCHUNK + c;
    float4* psent = (float4*)(ws + slot * SLOT_FLOATS);
    float4* pspan = psent + HDIM / 4;
    psent[tid] = make_float4(sx, sy, sz, sw);
    pspan[tid] = make_float4(px, py, pz, pw);
    if (tid == 0) ws[CNT_OFFSET + slot] = span_cnt;
}

__global__ __launch_bounds__(TPB) void pool_phase2(
    const int* __restrict__ review_nt,
    const int* __restrict__ reply_nt,
    const int* __restrict__ review_ss,
    const int* __restrict__ review_se,
    const int* __restrict__ reply_ss,
    const int* __restrict__ reply_se,
    const float* __restrict__ ws,
    float*       __restrict__ out)     // [4, N, H]
{
    const int n   = blockIdx.x;
    const int tid = threadIdx.x;
    const bool is_reply = (blockIdx.y != 0);

    const int* ntp = is_reply ? reply_nt : review_nt;
    const int* ssp = is_reply ? reply_ss : review_ss;
    const int* sep = is_reply ? reply_se : review_se;

    int nt, s[KSPAN], e[KSPAN], l_lo, l_hi;
    load_meta(ntp, ssp, sep, n, nt, s, e, l_lo, l_hi);

    const int c_lo = l_lo / CHUNK;
    const int c_hi = l_hi / CHUNK;
    const int item = (is_reply ? N_SENT : 0) + n;

    float sx = 0.f, sy = 0.f, sz = 0.f, sw = 0.f;
    float px = 0.f, py = 0.f, pz = 0.f, pw = 0.f;
    float span_cnt = 0.f;

    for (int c = c_lo; c <= c_hi; ++c) {
        const size_t slot = (size_t)item * NCHUNK + c;
        const float4* psent = (const float4*)(ws + slot * SLOT_FLOATS);
        const float4* pspan = psent + HDIM / 4;
        float4 a = psent[tid];
        float4 b = pspan[tid];
        sx += a.x; sy += a.y; sz += a.z; sw += a.w;
        px += b.x; py += b.y; pz += b.z; pw += b.w;
        span_cnt += ws[CNT_OFFSET + slot];
    }

    const float sent_cnt = (float)(nt < LSEQ - 1 ? nt : LSEQ - 1);
    const float inv_s = 1.0f / sent_cnt;
    const float smx = sx * inv_s, smy = sy * inv_s, smz = sz * inv_s, smw = sw * inv_s;

    const bool  has_span = (span_cnt > 0.5f);
    const float inv_p = 1.0f / fmaxf(span_cnt, 1.0f);
    const float ptx = has_span ? px * inv_p : smx;
    const float pty = has_span ? py * inv_p : smy;
    const float ptz = has_span ? pz * inv_p : smz;
    const float ptw = has_span ? pw * inv_p : smw;

    float* out_pt   = out + (is_reply ? 2 : 0) * (size_t)N_SENT * HDIM;
    float* out_sent = out + (is_reply ? 3 : 1) * (size_t)N_SENT * HDIM;
    float4* opt = (float4*)(out_pt   + (size_t)n * HDIM);
    float4* osn = (float4*)(out_sent + (size_t)n * HDIM);
    opt[tid] = make_float4(ptx, pty, ptz, ptw);
    osn[tid] = make_float4(smx, smy, smz, smw);
}

extern "C" void kernel_launch(void* const* d_in, const int* in_sizes, int n_in,
                              void* d_out, int out_size, void* d_ws, size_t ws_size,
                              hipStream_t stream) {
    const float* review_feat = (const float*)d_in[0];
    const float* reply_feat  = (const float*)d_in[1];
    const int*   review_nt   = (const int*)d_in[2];
    const int*   reply_nt    = (const int*)d_in[3];
    const int*   review_ss   = (const int*)d_in[4];
    const int*   review_se   = (const int*)d_in[5];
    const int*   reply_ss    = (const int*)d_in[6];
    const int*   reply_se    = (const int*)d_in[7];
    float* out = (float*)d_out;
    float* ws  = (float*)d_ws;

    dim3 g1(N_SENT, 2, NCHUNK);
    pool_phase1<<<g1, TPB, 0, stream>>>(
        review_feat, reply_feat, review_nt, reply_nt,
        review_ss, review_se, reply_ss, reply_se, ws);

    dim3 g2(N_SENT, 2);
    pool_phase2<<<g2, TPB, 0, stream>>>(
        review_nt, reply_nt, review_ss, review_se, reply_ss, reply_se, ws, out);
}

// Round 6
// 93.499 us; speedup vs baseline: 1.1926x; 1.1511x over previous
//
#include <hip/hip_runtime.h>

#define N_SENT 1024
#define LSEQ   128
#define HDIM   768
#define KSPAN  5
#define TPB    192   // HDIM / 4 float4 lanes
#define UNROLL 8

typedef float f32x4 __attribute__((ext_vector_type(4)));

__global__ __launch_bounds__(TPB) void bert_pool_kernel(
    const float* __restrict__ review_feat,   // [N, L, H]
    const float* __restrict__ reply_feat,    // [N, L, H]
    const int*   __restrict__ review_nt,     // [N]
    const int*   __restrict__ reply_nt,      // [N]
    const int*   __restrict__ review_ss,     // [N, K]
    const int*   __restrict__ review_se,     // [N, K]
    const int*   __restrict__ reply_ss,      // [N, K]
    const int*   __restrict__ reply_se,      // [N, K]
    float*       __restrict__ out)           // [4, N, H]: review_pt, review_sent, reply_pt, reply_sent
{
    const int item = blockIdx.x;             // tensor-interleaved: adjacent blocks alternate tensors
    const int n    = item >> 1;
    const int tid  = threadIdx.x;
    const bool is_reply = (item & 1) != 0;

    const float* feat = is_reply ? reply_feat : review_feat;
    const int*   ntp  = is_reply ? reply_nt   : review_nt;
    const int*   ssp  = is_reply ? reply_ss   : review_ss;
    const int*   sep  = is_reply ? reply_se   : review_se;
    float* out_pt   = out + (is_reply ? 2 : 0) * (size_t)N_SENT * HDIM;
    float* out_sent = out + (is_reply ? 3 : 1) * (size_t)N_SENT * HDIM;

    const int nt = ntp[n];

    int s[KSPAN], e[KSPAN];
    int l_lo = 1, l_hi = nt;
#pragma unroll
    for (int k = 0; k < KSPAN; ++k) {
        s[k] = ssp[(size_t)n * KSPAN + k];
        e[k] = sep[(size_t)n * KSPAN + k];
        if (s[k] <= e[k]) {              // valid span
            if (s[k] < l_lo) l_lo = s[k];
            if (e[k] > l_hi) l_hi = e[k];
        }
    }
    if (l_lo < 0) l_lo = 0;
    if (l_hi > LSEQ - 1) l_hi = LSEQ - 1;

    const f32x4* frow = (const f32x4*)(feat + (size_t)n * LSEQ * HDIM);

    float sx = 0.f, sy = 0.f, sz = 0.f, sw = 0.f;   // sentence accum
    float px = 0.f, py = 0.f, pz = 0.f, pw = 0.f;   // span accum
    float span_cnt = 0.f;

    for (int l0 = l_lo; l0 <= l_hi; l0 += UNROLL) {
        f32x4 v[UNROLL];
        float ms[UNROLL], mp[UNROLL];
#pragma unroll
        for (int i = 0; i < UNROLL; ++i) {
            const int  l    = l0 + i;
            const bool live = (l <= l_hi);
            const int  lc   = live ? l : l_hi;           // clamped dup -> cache hit
            v[i] = __builtin_nontemporal_load(&frow[(size_t)lc * (HDIM / 4) + tid]);
            ms[i] = (live && l >= 1 && l <= nt) ? 1.0f : 0.0f;
            bool insp = false;
#pragma unroll
            for (int k = 0; k < KSPAN; ++k)
                insp = insp || ((l >= s[k]) && (l <= e[k]));
            mp[i] = (live && insp) ? 1.0f : 0.0f;
        }
#pragma unroll
        for (int i = 0; i < UNROLL; ++i) {
            sx = fmaf(v[i].x, ms[i], sx);
            sy = fmaf(v[i].y, ms[i], sy);
            sz = fmaf(v[i].z, ms[i], sz);
            sw = fmaf(v[i].w, ms[i], sw);
            px = fmaf(v[i].x, mp[i], px);
            py = fmaf(v[i].y, mp[i], py);
            pz = fmaf(v[i].z, mp[i], pz);
            pw = fmaf(v[i].w, mp[i], pw);
            span_cnt += mp[i];
        }
    }

    // sentence mean: count of positions p with 1 <= p <= nt, p < L
    const float sent_cnt = (float)(nt < LSEQ - 1 ? nt : LSEQ - 1);
    const float inv_s = 1.0f / sent_cnt;
    const float smx = sx * inv_s, smy = sy * inv_s, smz = sz * inv_s, smw = sw * inv_s;

    const bool  has_span = (span_cnt > 0.5f);
    const float inv_p = 1.0f / fmaxf(span_cnt, 1.0f);
    const float ptx = has_span ? px * inv_p : smx;
    const float pty = has_span ? py * inv_p : smy;
    const float ptz = has_span ? pz * inv_p : smz;
    const float ptw = has_span ? pw * inv_p : smw;

    f32x4 rpt = {ptx, pty, ptz, ptw};
    f32x4 rsn = {smx, smy, smz, smw};
    __builtin_nontemporal_store(rpt, &((f32x4*)(out_pt   + (size_t)n * HDIM))[tid]);
    __builtin_nontemporal_store(rsn, &((f32x4*)(out_sent + (size_t)n * HDIM))[tid]);
}

extern "C" void kernel_launch(void* const* d_in, const int* in_sizes, int n_in,
                              void* d_out, int out_size, void* d_ws, size_t ws_size,
                              hipStream_t stream) {
    const float* review_feat = (const float*)d_in[0];
    const float* reply_feat  = (const float*)d_in[1];
    const int*   review_nt   = (const int*)d_in[2];
    const int*   reply_nt    = (const int*)d_in[3];
    const int*   review_ss   = (const int*)d_in[4];
    const int*   review_se   = (const int*)d_in[5];
    const int*   reply_ss    = (const int*)d_in[6];
    const int*   reply_se    = (const int*)d_in[7];
    float* out = (float*)d_out;

    bert_pool_kernel<<<2 * N_SENT, TPB, 0, stream>>>(
        review_feat, reply_feat, review_nt, reply_nt,
        review_ss, review_se, reply_ss, reply_se, out);
}